// Round 1
// baseline (599.104 us; speedup 1.0000x reference)
//
#include <hip/hip_runtime.h>
#include <math.h>

#define PS   65
#define NPIX (PS * PS)
#define NBINS 128

// triangular pooling weight for offset t in [0,26): (13 - |t - 12.5|)/13
__device__ __forceinline__ float triw(int t) {
    return (13.0f - fabsf((float)t - 12.5f)) * (1.0f / 13.0f);
}

__global__ __launch_bounds__(256) void sift_desc_kernel(
        const float* __restrict__ img, float* __restrict__ out) {
    const int s   = blockIdx.x;     // slice index in (B, C, 8, 8) row-major
    const int tid = threadIdx.x;
    const int wid = tid >> 6;       // wave id, 0..3

    // decode slice -> (b, c, tile_i, tile_j)
    const int b   = s / 192;        // C*8*8 = 192
    const int rem = s - b * 192;
    const int c   = rem >> 6;
    const int t2  = rem & 63;
    const int pi  = t2 >> 3;
    const int pj  = t2 & 7;
    const float* src = img + ((size_t)((b * 3 + c) * 520 + pi * 65)) * 520 + pj * 65;

    __shared__ float patch[NPIX];        // 65*65 floats
    __shared__ float hist[4][NBINS];     // per-wave histograms
    __shared__ float gtab[PS];           // unnormalized 1D gaussian
    __shared__ float fin[NBINS];
    __shared__ float redv[2];

    // zero per-wave histograms
    float* hflat = &hist[0][0];
    for (int k = tid; k < 4 * NBINS; k += 256) hflat[k] = 0.0f;

    // gaussian table: sigma = 65/sqrt(2) -> 2*sigma^2 = 65^2 = 4225
    if (tid < PS) {
        float d = (float)(tid - 32);
        gtab[tid] = expf(-(d * d) * (1.0f / 4225.0f));
    }

    // stage patch into LDS (coalesced-ish row loads)
    for (int p = tid; p < NPIX; p += 256) {
        int y = p / 65;
        int x = p - y * 65;
        patch[p] = src[y * 520 + x];
    }
    __syncthreads();

    // normalize gaussian: invZ2 = 1/Z^2, weight(y,x) = gtab[y]*gtab[x]*invZ2
    if (tid < 64) {
        float v = gtab[tid] + ((tid == 0) ? gtab[64] : 0.0f);
        #pragma unroll
        for (int off = 32; off > 0; off >>= 1) v += __shfl_down(v, off);
        if (tid == 0) redv[0] = 1.0f / (v * v);
    }
    __syncthreads();
    const float invZ2 = redv[0];
    float* myhist = hist[wid];

    // main per-pixel loop
    for (int p = tid; p < NPIX; p += 256) {
        int y = p / 65;
        int x = p - y * 65;
        int row = y * 65;
        float lft = patch[row + (x > 0 ? x - 1 : 0)];
        float rgt = patch[row + (x < 64 ? x + 1 : 64)];
        float top = patch[(y > 0 ? y - 1 : 0) * 65 + x];
        float bot = patch[(y < 64 ? y + 1 : 64) * 65 + x];
        float gx = (rgt - lft) * 0.5f;
        float gy = (bot - top) * 0.5f;

        float mag = sqrtf(gx * gx + gy * gy + 1e-10f) * (gtab[y] * gtab[x] * invZ2);

        // o_big = 8*(atan2(gy,gx+eps)+2pi)/(2pi) = atan2*(4/pi) + 8, in [4,12]
        float ob = atan2f(gy, gx + 1e-10f) * (float)(4.0 / M_PI) + 8.0f;
        float fl = floorf(ob);
        float fr = ob - fl;
        int a0 = ((int)fl) & 7;
        int a1 = (a0 + 1) & 7;
        float wa0 = (1.0f - fr) * mag;
        float wa1 = fr * mag;
        int ba0 = a0 << 4;
        int ba1 = a1 << 4;

        // spatial bins: output bin i covers input [i*16-6, i*16+19]
        int uy = y + 6, ux = x + 6;
        int iy1 = uy >> 4, ty1 = uy & 15;   // candidate bin A (t in [0,15])
        int ix1 = ux >> 4, tx1 = ux & 15;
        float wyA = (iy1 <= 3) ? triw(ty1) : 0.0f;
        float wyB = (iy1 >= 1 && ty1 <= 9) ? triw(ty1 + 16) : 0.0f; // bin iy1-1
        float wxA = (ix1 <= 3) ? triw(tx1) : 0.0f;
        float wxB = (ix1 >= 1 && tx1 <= 9) ? triw(tx1 + 16) : 0.0f;

        if (wyA > 0.0f) {
            int by = iy1 << 2;
            if (wxA > 0.0f) {
                float w = wyA * wxA;
                int k = by + ix1;
                atomicAdd(&myhist[ba0 + k], wa0 * w);
                atomicAdd(&myhist[ba1 + k], wa1 * w);
            }
            if (wxB > 0.0f) {
                float w = wyA * wxB;
                int k = by + ix1 - 1;
                atomicAdd(&myhist[ba0 + k], wa0 * w);
                atomicAdd(&myhist[ba1 + k], wa1 * w);
            }
        }
        if (wyB > 0.0f) {
            int by = (iy1 - 1) << 2;
            if (wxA > 0.0f) {
                float w = wyB * wxA;
                int k = by + ix1;
                atomicAdd(&myhist[ba0 + k], wa0 * w);
                atomicAdd(&myhist[ba1 + k], wa1 * w);
            }
            if (wxB > 0.0f) {
                float w = wyB * wxB;
                int k = by + ix1 - 1;
                atomicAdd(&myhist[ba0 + k], wa0 * w);
                atomicAdd(&myhist[ba1 + k], wa1 * w);
            }
        }
    }
    __syncthreads();

    // reduce per-wave histograms
    if (tid < NBINS) {
        fin[tid] = hist[0][tid] + hist[1][tid] + hist[2][tid] + hist[3][tid];
    }
    __syncthreads();

    // first L2 norm
    if (tid < 64) {
        float sq = fin[tid] * fin[tid] + fin[tid + 64] * fin[tid + 64];
        #pragma unroll
        for (int off = 32; off > 0; off >>= 1) sq += __shfl_down(sq, off);
        if (tid == 0) redv[0] = sq;
    }
    __syncthreads();
    float inv1 = 1.0f / fmaxf(sqrtf(redv[0]), 1e-12f);
    if (tid < NBINS) {
        // values are non-negative; clip upper bound 0.2
        fin[tid] = fminf(fin[tid] * inv1, 0.2f);
    }
    __syncthreads();

    // second L2 norm
    if (tid < 64) {
        float sq = fin[tid] * fin[tid] + fin[tid + 64] * fin[tid + 64];
        #pragma unroll
        for (int off = 32; off > 0; off >>= 1) sq += __shfl_down(sq, off);
        if (tid == 0) redv[1] = sq;
    }
    __syncthreads();
    float inv2 = 1.0f / fmaxf(sqrtf(redv[1]), 1e-12f);
    if (tid < NBINS) {
        out[(size_t)s * NBINS + tid] = fin[tid] * inv2;
    }
}

extern "C" void kernel_launch(void* const* d_in, const int* in_sizes, int n_in,
                              void* d_out, int out_size, void* d_ws, size_t ws_size,
                              hipStream_t stream) {
    const float* img = (const float*)d_in[0];
    float* out = (float*)d_out;
    // B = elems / (3*520*520); slices = B * 3 * 64
    const int B = in_sizes[0] / (3 * 520 * 520);
    const int nslices = B * 192;
    sift_desc_kernel<<<nslices, 256, 0, stream>>>(img, out);
}

// Round 2
// 164.114 us; speedup vs baseline: 3.6505x; 3.6505x over previous
//
#include <hip/hip_runtime.h>
#include <math.h>

#define PS     65
#define NPIX   (PS * PS)
#define SPITCH 37           // row pitch for S[65][32] -> padded to 37 (bank spread)

__global__ __launch_bounds__(256) void sift_desc_kernel(
        const float* __restrict__ img, float* __restrict__ out) {
    const int s   = blockIdx.x;     // slice index in (B, C, 8, 8) row-major
    const int tid = threadIdx.x;

    // decode slice -> (b, c, tile_i, tile_j)
    const int b   = s / 192;        // C*8*8 = 192
    const int rem = s - b * 192;
    const int c   = rem >> 6;
    const int t2  = rem & 63;
    const int pi  = t2 >> 3;
    const int pj  = t2 & 7;
    const float* src = img + ((size_t)((b * 3 + c) * 520 + pi * 65)) * 520 + pj * 65;

    __shared__ float patch[NPIX];          // 65x65 tile
    __shared__ float S[PS * SPITCH];       // column-pass partials: [y][a*4+j]
    __shared__ float gtab[PS];             // normalized 1D gaussian
    __shared__ float fin[128];
    __shared__ float redv[2];

    // gaussian table: sigma = 65/sqrt(2) -> 2*sigma^2 = 4225
    if (tid < PS) {
        float d = (float)(tid - 32);
        gtab[tid] = expf(-(d * d) * (1.0f / 4225.0f));
    }

    // stage patch into LDS (coalesced row loads)
    for (int p = tid; p < NPIX; p += 256) {
        int y = p / 65;
        int x = p - y * 65;
        patch[p] = src[y * 520 + x];
    }
    __syncthreads();

    // normalize gaussian in-place: gtab[i] /= Z
    if (tid < 64) {
        float v = gtab[tid] + ((tid == 0) ? gtab[64] : 0.0f);
        #pragma unroll
        for (int off = 32; off > 0; off >>= 1) v += __shfl_down(v, off);
        if (tid == 0) redv[0] = 1.0f / v;
    }
    __syncthreads();
    const float invZ = redv[0];
    if (tid < PS) gtab[tid] *= invZ;
    __syncthreads();

    // ---- column pass: entry e = (y, xwin j); accumulate 8 angular bins in regs
    for (int e = tid; e < PS * 4; e += 256) {
        const int y  = e >> 2;
        const int j  = e & 3;
        const int xs = j * 16 - 6;                // window start (zero-pad region skipped)
        const int x0 = (xs > 0) ? xs : 0;
        const int x1 = (xs + 25 < 64) ? xs + 25 : 64;

        float a0r = 0.f, a1r = 0.f, a2r = 0.f, a3r = 0.f;
        float a4r = 0.f, a5r = 0.f, a6r = 0.f, a7r = 0.f;

        const int   row  = y * 65;
        const int   rowm = (y > 0  ? y - 1 : 0)  * 65;
        const int   rowp = (y < 64 ? y + 1 : 64) * 65;
        const float gyw  = gtab[y];

        for (int x = x0; x <= x1; ++x) {
            float lft = patch[row + (x > 0  ? x - 1 : 0)];
            float rgt = patch[row + (x < 64 ? x + 1 : 64)];
            float top = patch[rowm + x];
            float bot = patch[rowp + x];
            float gx = (rgt - lft) * 0.5f;
            float gy = (bot - top) * 0.5f;

            float mag = sqrtf(gx * gx + gy * gy + 1e-10f) * (gyw * gtab[x]);

            // o_big = atan2*(4/pi) + 8  in [4,12]
            float ob = atan2f(gy, gx + 1e-10f) * (float)(4.0 / M_PI) + 8.0f;
            float fl = floorf(ob);
            float fr = ob - fl;
            int   b0 = ((int)fl) & 7;
            int   b1 = (b0 + 1) & 7;

            // triangular x-weight: t = x - xs in [0,26)
            float tt = (float)(x - xs);
            float wx = (13.0f - fabsf(tt - 12.5f)) * (1.0f / 13.0f);
            float w0 = (1.0f - fr) * mag * wx;
            float w1 = fr * mag * wx;

            a0r += (b0 == 0 ? w0 : 0.f) + (b1 == 0 ? w1 : 0.f);
            a1r += (b0 == 1 ? w0 : 0.f) + (b1 == 1 ? w1 : 0.f);
            a2r += (b0 == 2 ? w0 : 0.f) + (b1 == 2 ? w1 : 0.f);
            a3r += (b0 == 3 ? w0 : 0.f) + (b1 == 3 ? w1 : 0.f);
            a4r += (b0 == 4 ? w0 : 0.f) + (b1 == 4 ? w1 : 0.f);
            a5r += (b0 == 5 ? w0 : 0.f) + (b1 == 5 ? w1 : 0.f);
            a6r += (b0 == 6 ? w0 : 0.f) + (b1 == 6 ? w1 : 0.f);
            a7r += (b0 == 7 ? w0 : 0.f) + (b1 == 7 ? w1 : 0.f);
        }

        const int base = y * SPITCH + j;       // S[y][a*4 + j]
        S[base +  0] = a0r;
        S[base +  4] = a1r;
        S[base +  8] = a2r;
        S[base + 12] = a3r;
        S[base + 16] = a4r;
        S[base + 20] = a5r;
        S[base + 24] = a6r;
        S[base + 28] = a7r;
    }
    __syncthreads();

    // ---- row pass: 128 outputs, bin index = a*16 + i*4 + j
    if (tid < 128) {
        const int a  = tid >> 4;
        const int i  = (tid >> 2) & 3;
        const int j  = tid & 3;
        const int ys = i * 16 - 6;
        float v = 0.f;
        #pragma unroll
        for (int t = 0; t < 26; ++t) {
            int y = ys + t;
            if (y >= 0 && y <= 64) {
                float wy = (13.0f - fabsf((float)t - 12.5f)) * (1.0f / 13.0f);
                v += wy * S[y * SPITCH + a * 4 + j];
            }
        }
        fin[tid] = v;
    }
    __syncthreads();

    // first L2 norm
    if (tid < 64) {
        float sq = fin[tid] * fin[tid] + fin[tid + 64] * fin[tid + 64];
        #pragma unroll
        for (int off = 32; off > 0; off >>= 1) sq += __shfl_down(sq, off);
        if (tid == 0) redv[0] = sq;
    }
    __syncthreads();
    float inv1 = 1.0f / fmaxf(sqrtf(redv[0]), 1e-12f);
    if (tid < 128) {
        fin[tid] = fminf(fin[tid] * inv1, 0.2f);   // values non-negative; clip hi
    }
    __syncthreads();

    // second L2 norm
    if (tid < 64) {
        float sq = fin[tid] * fin[tid] + fin[tid + 64] * fin[tid + 64];
        #pragma unroll
        for (int off = 32; off > 0; off >>= 1) sq += __shfl_down(sq, off);
        if (tid == 0) redv[1] = sq;
    }
    __syncthreads();
    float inv2 = 1.0f / fmaxf(sqrtf(redv[1]), 1e-12f);
    if (tid < 128) {
        out[(size_t)s * 128 + tid] = fin[tid] * inv2;
    }
}

extern "C" void kernel_launch(void* const* d_in, const int* in_sizes, int n_in,
                              void* d_out, int out_size, void* d_ws, size_t ws_size,
                              hipStream_t stream) {
    const float* img = (const float*)d_in[0];
    float* out = (float*)d_out;
    const int B = in_sizes[0] / (3 * 520 * 520);
    const int nslices = B * 192;
    sift_desc_kernel<<<nslices, 256, 0, stream>>>(img, out);
}

// Round 3
// 138.253 us; speedup vs baseline: 4.3334x; 1.1871x over previous
//
#include <hip/hip_runtime.h>
#include <math.h>

#define PS     65
#define NPIX   (PS * PS)
#define SPITCH 37           // row pitch for S[65][32] -> padded to 37 (bank spread)

// atan(t)*(4/pi) for t in [0,1], degree-9 odd minimax (Hastings), |err|<=1.3e-5
#define C0  1.2730689f
#define C1 -0.4205505f
#define C2  0.2293627f
#define C3 -0.1083947f
#define C4  0.0265281f

__global__ __launch_bounds__(256) void sift_desc_kernel(
        const float* __restrict__ img, float* __restrict__ out) {
    const int s   = blockIdx.x;     // slice index in (B, C, 8, 8) row-major
    const int tid = threadIdx.x;

    // decode slice -> (b, c, tile_i, tile_j)
    const int b   = s / 192;        // C*8*8 = 192
    const int rem = s - b * 192;
    const int c   = rem >> 6;
    const int t2  = rem & 63;
    const int pi  = t2 >> 3;
    const int pj  = t2 & 7;
    const float* src = img + ((size_t)((b * 3 + c) * 520 + pi * 65)) * 520 + pj * 65;

    __shared__ float patch[NPIX];          // 65x65 tile
    __shared__ float S[PS * SPITCH];       // column-pass partials: [y][a*4+j]
    __shared__ float gtab[PS];             // normalized 1D gaussian
    __shared__ float fin[128];
    __shared__ float redv[2];

    // gaussian table: sigma = 65/sqrt(2) -> 2*sigma^2 = 4225
    if (tid < PS) {
        float d = (float)(tid - 32);
        gtab[tid] = expf(-(d * d) * (1.0f / 4225.0f));
    }

    // stage patch into LDS (coalesced row loads)
    for (int p = tid; p < NPIX; p += 256) {
        int y = p / 65;
        int x = p - y * 65;
        patch[p] = src[y * 520 + x];
    }
    __syncthreads();

    // normalize gaussian in-place: gtab[i] /= Z
    if (tid < 64) {
        float v = gtab[tid] + ((tid == 0) ? gtab[64] : 0.0f);
        #pragma unroll
        for (int off = 32; off > 0; off >>= 1) v += __shfl_down(v, off);
        if (tid == 0) redv[0] = 1.0f / v;
    }
    __syncthreads();
    const float invZ = redv[0];
    if (tid < PS) gtab[tid] *= invZ;
    __syncthreads();

    // ---- column pass: entry e = (y, xwin j); accumulate 8 angular bins in regs
    for (int e = tid; e < PS * 4; e += 256) {
        const int y  = e >> 2;
        const int j  = e & 3;
        const int xs = j * 16 - 6;                // window start (zero-pad region skipped)
        const int x0 = (xs > 0) ? xs : 0;
        const int x1 = (xs + 25 < 64) ? xs + 25 : 64;

        float a0r = 0.f, a1r = 0.f, a2r = 0.f, a3r = 0.f;
        float a4r = 0.f, a5r = 0.f, a6r = 0.f, a7r = 0.f;

        const int   row  = y * 65;
        const int   rowm = (y > 0  ? y - 1 : 0)  * 65;
        const int   rowp = (y < 64 ? y + 1 : 64) * 65;
        const float gyw  = gtab[y];

        for (int x = x0; x <= x1; ++x) {
            float lft = patch[row + (x > 0  ? x - 1 : 0)];
            float rgt = patch[row + (x < 64 ? x + 1 : 64)];
            float top = patch[rowm + x];
            float bot = patch[rowp + x];
            float gx = (rgt - lft) * 0.5f;
            float gy = (bot - top) * 0.5f;

            float mag = sqrtf(gx * gx + gy * gy + 1e-10f) * (gyw * gtab[x]);

            // octant-decomposed atan2 in octant units: ob = atan2*(4/pi)+8
            float gxe = gx + 1e-10f;
            float ax = fabsf(gxe), ay = fabsf(gy);
            float mn = fminf(ax, ay);
            float mx = fmaxf(ax, ay);
            float t  = mn * __builtin_amdgcn_rcpf(fmaxf(mx, 1e-35f));
            float ss = t * t;
            float u  = t * (C0 + ss * (C1 + ss * (C2 + ss * (C3 + ss * C4))));
            float A  = (ay > ax)      ? 2.0f - u : u;
            A        = (gxe < 0.0f)   ? 4.0f - A : A;
            A        = (gy  < 0.0f)   ? -A       : A;
            float ob = A + 8.0f;                       // in [4,12]
            float fl = floorf(ob);
            float fr = ob - fl;
            int   b0 = ((int)fl) & 7;

            // triangular x-weight: t = x - xs in [0,26)
            float tt = (float)(x - xs);
            float wx = (13.0f - fabsf(tt - 12.5f)) * (1.0f / 13.0f);
            float mw = mag * wx;
            float w1 = fr * mw;
            float w0 = mw - w1;

            // bin k += w0 if b0==k, += w1 if b0==(k-1)&7  (each cmp used twice)
            float v;
            v = (b0 == 0) ? w0 : 0.f; v = (b0 == 7) ? w1 : v; a0r += v;
            v = (b0 == 1) ? w0 : 0.f; v = (b0 == 0) ? w1 : v; a1r += v;
            v = (b0 == 2) ? w0 : 0.f; v = (b0 == 1) ? w1 : v; a2r += v;
            v = (b0 == 3) ? w0 : 0.f; v = (b0 == 2) ? w1 : v; a3r += v;
            v = (b0 == 4) ? w0 : 0.f; v = (b0 == 3) ? w1 : v; a4r += v;
            v = (b0 == 5) ? w0 : 0.f; v = (b0 == 4) ? w1 : v; a5r += v;
            v = (b0 == 6) ? w0 : 0.f; v = (b0 == 5) ? w1 : v; a6r += v;
            v = (b0 == 7) ? w0 : 0.f; v = (b0 == 6) ? w1 : v; a7r += v;
        }

        const int base = y * SPITCH + j;       // S[y][a*4 + j]
        S[base +  0] = a0r;
        S[base +  4] = a1r;
        S[base +  8] = a2r;
        S[base + 12] = a3r;
        S[base + 16] = a4r;
        S[base + 20] = a5r;
        S[base + 24] = a6r;
        S[base + 28] = a7r;
    }
    __syncthreads();

    // ---- row pass: 128 outputs, bin index = a*16 + i*4 + j
    if (tid < 128) {
        const int a  = tid >> 4;
        const int i  = (tid >> 2) & 3;
        const int j  = tid & 3;
        const int ys = i * 16 - 6;
        float v = 0.f;
        #pragma unroll
        for (int t = 0; t < 26; ++t) {
            int y = ys + t;
            if (y >= 0 && y <= 64) {
                float wy = (13.0f - fabsf((float)t - 12.5f)) * (1.0f / 13.0f);
                v += wy * S[y * SPITCH + a * 4 + j];
            }
        }
        fin[tid] = v;
    }
    __syncthreads();

    // first L2 norm
    if (tid < 64) {
        float sq = fin[tid] * fin[tid] + fin[tid + 64] * fin[tid + 64];
        #pragma unroll
        for (int off = 32; off > 0; off >>= 1) sq += __shfl_down(sq, off);
        if (tid == 0) redv[0] = sq;
    }
    __syncthreads();
    float inv1 = 1.0f / fmaxf(sqrtf(redv[0]), 1e-12f);
    if (tid < 128) {
        fin[tid] = fminf(fin[tid] * inv1, 0.2f);   // values non-negative; clip hi
    }
    __syncthreads();

    // second L2 norm
    if (tid < 64) {
        float sq = fin[tid] * fin[tid] + fin[tid + 64] * fin[tid + 64];
        #pragma unroll
        for (int off = 32; off > 0; off >>= 1) sq += __shfl_down(sq, off);
        if (tid == 0) redv[1] = sq;
    }
    __syncthreads();
    float inv2 = 1.0f / fmaxf(sqrtf(redv[1]), 1e-12f);
    if (tid < 128) {
        out[(size_t)s * 128 + tid] = fin[tid] * inv2;
    }
}

extern "C" void kernel_launch(void* const* d_in, const int* in_sizes, int n_in,
                              void* d_out, int out_size, void* d_ws, size_t ws_size,
                              hipStream_t stream) {
    const float* img = (const float*)d_in[0];
    float* out = (float*)d_out;
    const int B = in_sizes[0] / (3 * 520 * 520);
    const int nslices = B * 192;
    sift_desc_kernel<<<nslices, 256, 0, stream>>>(img, out);
}